// Round 11
// baseline (112.441 us; speedup 1.0000x reference)
//
#include <hip/hip_runtime.h>
#include <stdint.h>

#pragma clang fp contract(off)

// PRNG: jax_threefry_partitionable 32-bit random_bits = o0 ^ o1 (VERIFIED round 3)
// r8/r9/r10 all 57.5 +- 0.1% despite big K1/K2 internal changes -> kernels are
// pinned (K1 VALU ~12us, K2 write-BW ~18us); residual sits at the dispatch
// boundary. r11: SINGLE dispatch — fused kernel, grid 512 (2 blocks/CU
// guaranteed co-residency), manual poison-tolerant grid barrier in ws.

#define BB 64
#define NN 4096
#define MM 128
#define LL 21
#define NTOT (BB * NN)                           // 262144 rois
#define DELTA_ELEMS ((size_t)BB * NN * LL * 4)   // 22020096 floats
#define NBLK 512

__host__ __device__ __forceinline__ uint32_t rotl32(uint32_t v, int s) {
  return (v << s) | (v >> (32 - s));
}

// Threefry-2x32, 20 rounds (JAX's threefry2x32).
__host__ __device__ inline void threefry2x32(uint32_t k0, uint32_t k1,
                                             uint32_t x0, uint32_t x1,
                                             uint32_t* o0, uint32_t* o1) {
  const uint32_t ks2 = k0 ^ k1 ^ 0x1BD11BDAu;
  x0 += k0; x1 += k1;
#define TF_R(r) do { x0 += x1; x1 = rotl32(x1, (r)); x1 ^= x0; } while (0)
  TF_R(13); TF_R(15); TF_R(26); TF_R(6);
  x0 += k1;  x1 += ks2 + 1u;
  TF_R(17); TF_R(29); TF_R(16); TF_R(24);
  x0 += ks2; x1 += k0 + 2u;
  TF_R(13); TF_R(15); TF_R(26); TF_R(6);
  x0 += k0;  x1 += k1 + 3u;
  TF_R(17); TF_R(29); TF_R(16); TF_R(24);
  x0 += k1;  x1 += ks2 + 4u;
  TF_R(13); TF_R(15); TF_R(26); TF_R(6);
  x0 += ks2; x1 += k0 + 5u;
#undef TF_R
  *o0 = x0; *o1 = x1;
}

__device__ __forceinline__ uint32_t jax_bits32(uint32_t ka, uint32_t kb, uint32_t idx) {
  uint32_t o0, o1;
  threefry2x32(ka, kb, 0u, idx, &o0, &o1);   // counter (hi=0, lo=idx)
  return o0 ^ o1;                            // partitionable 32-bit fold
}

// jax.random.randint(key, (B,N), 1, 1280): span=1279, mult=(2^16%1279)^2%1279=882
__device__ __forceinline__ uint32_t jax_randint_1_1280(uint32_t k1a, uint32_t k1b,
                                                       uint32_t k2a, uint32_t k2b,
                                                       uint32_t idx) {
  const uint32_t hi = jax_bits32(k1a, k1b, idx);
  const uint32_t lo = jax_bits32(k2a, k2b, idx);
  const uint32_t off = ((hi % 1279u) * 882u + (lo % 1279u)) % 1279u;
  return 1u + off;
}

__device__ __forceinline__ float4 compute_delta(const float4 r, const float4 g) {
  float bh = r.z - r.x, bw = r.w - r.y;
  const float bcy = r.x + 0.5f * bh, bcx = r.y + 0.5f * bw;
  const float gh = g.z - g.x, gw = g.w - g.y;
  const float gcy = g.x + 0.5f * gh, gcx = g.y + 0.5f * gw;
  if (bw == 0.0f) bw = 1e-3f;
  if (bh == 0.0f) bh = 1e-3f;
  const float dx = (gcx - bcx) / bw;
  const float dy = (gcy - bcy) / bh;
  const float dw = (gw == 0.0f) ? 0.0f : logf(gw / bw);
  const float dh = (gh == 0.0f) ? 0.0f : logf(gh / bh);
  float4 dv;
  dv.x = dy / 0.1f; dv.y = dx / 0.1f; dv.z = dh / 0.2f; dv.w = dw / 0.2f;
  return dv;
}

// ---------------- Fused single-dispatch kernel ----------------
// grid 512 x 256. Block br: row b = br>>3, rois [wbase, wbase+512) of the row.
// Phase 1: IoU+rand pack for its 512 rois. Grid barrier. Phase 2: row-wide
// selection recompute (dup x8 per row) + coalesced write of its 2 windows.
// Barrier counters: A (incremented), B (never written). Both share the uniform
// 0xAA ws poison -> target = B + roundup512(A_old - B) is identical across the
// replay's 512 arrivals, monotone across graph replays, no init required.
__global__ __launch_bounds__(256, 2) void mega_kernel(
    const float* __restrict__ roi, const float* __restrict__ gt,
    const int* __restrict__ glab, uint32_t* __restrict__ packed,
    uint32_t* __restrict__ barA, const uint32_t* __restrict__ barB,
    float* __restrict__ out,
    uint32_t k1a, uint32_t k1b, uint32_t k2a, uint32_t k2b) {
  __shared__ float4 gtb[MM];
  __shared__ uint32_t hist[1280];
  __shared__ uint32_t scan[257];        // scan[256] = 0 sentinel
  __shared__ uint32_t wsum[4];
  __shared__ unsigned char selb[512];   // this block's 2 windows only
  __shared__ float4 sdv[256];
  __shared__ int slbl[256];
  __shared__ int s_thr;
  __shared__ int s_take;

  const int br = blockIdx.x;
  const int b = br >> 3;                 // row
  const int wbase = (br & 7) << 9;       // first in-row roi of this block (x512)
  const int t = threadIdx.x;
  const int lane = t & 63;
  const int wid = t >> 6;

  // ================= Phase 1: IoU argmax + rand pack (2 rois) =================
  const int i0 = b * NN + wbase + t;
  const int i1 = i0 + 256;
  const float4 r0 = ((const float4*)roi)[i0];
  const float4 r1 = ((const float4*)roi)[i1];
  if (t < MM) gtb[t] = ((const float4*)gt)[b * MM + t];
  __syncthreads();
  const float ba0 = (r0.z - r0.x) * (r0.w - r0.y);
  const float ba1 = (r1.z - r1.x) * (r1.w - r1.y);
  float best0 = -1.0f, best1 = -1.0f;
  int bm0 = 0, bm1 = 0;
  #pragma unroll 4
  for (int m = 0; m < MM; ++m) {
    const float4 g = gtb[m];                        // one LDS b128 serves 2 rois
    const float garea = (g.z - g.x) * (g.w - g.y);
    {
      const float xt = fmaxf(r0.y, g.y);
      const float yt = fmaxf(r0.x, g.x);
      const float xb = fminf(r0.w, g.w);
      const float yb = fminf(r0.z, g.z);
      const float inter = fmaxf(xb - xt, 0.0f) * fmaxf(yb - yt, 0.0f);
      const float iou = inter / ((ba0 + garea) - inter);   // IEEE div, bit-exact
      if (iou > best0) { best0 = iou; bm0 = m; }
    }
    {
      const float xt = fmaxf(r1.y, g.y);
      const float yt = fmaxf(r1.x, g.x);
      const float xb = fminf(r1.w, g.w);
      const float yb = fminf(r1.z, g.z);
      const float inter = fmaxf(xb - xt, 0.0f) * fmaxf(yb - yt, 0.0f);
      const float iou = inter / ((ba1 + garea) - inter);
      if (iou > best1) { best1 = iou; bm1 = m; }
    }
  }
  const uint32_t rnd0 = jax_randint_1_1280(k1a, k1b, k2a, k2b, (uint32_t)i0);
  const uint32_t rnd1 = jax_randint_1_1280(k1a, k1b, k2a, k2b, (uint32_t)i1);
  const uint32_t pk0 = (uint32_t)bm0 | ((best0 > 0.5f) ? (rnd0 << 7) : 0u);
  const uint32_t pk1 = (uint32_t)bm1 | ((best1 > 0.5f) ? (rnd1 << 7) : 0u);
  packed[i0] = pk0;
  packed[i1] = pk1;

  // ================= Grid barrier (poison-tolerant A/B scheme) =================
  __syncthreads();                       // drains this block's packed stores
  if (t == 0) {
    const uint32_t base = __hip_atomic_load((uint32_t*)barB, __ATOMIC_RELAXED,
                                            __HIP_MEMORY_SCOPE_AGENT);
    const uint32_t old = __hip_atomic_fetch_add(barA, 1u, __ATOMIC_RELEASE,
                                                __HIP_MEMORY_SCOPE_AGENT);
    const uint32_t target = base + ((((old - base) >> 9) + 1u) << 9);  // +512
    int guard = 0;
    while ((int32_t)(__hip_atomic_load(barA, __ATOMIC_ACQUIRE,
                                       __HIP_MEMORY_SCOPE_AGENT) - target) < 0) {
      __builtin_amdgcn_s_sleep(2);
      if (++guard > (1 << 21)) break;    // safety valve: fail loud, never hang
    }
  }
  __syncthreads();
  __threadfence();                       // L1/L2 acquire for remote packed reads

  // ================= Phase 2: selection recompute + windowed write ============
  // Speculative per-roi work from phase-1 registers (overlaps scans).
  const int mi0 = (int)(pk0 & 127u);
  const int mi1 = (int)(pk1 & 127u);
  const int lbl0g = glab[b * MM + mi0];
  const int lbl1g = glab[b * MM + mi1];
  const uint4* p4 = (const uint4*)(packed + (size_t)b * NN);
  const uint4 w0 = p4[t * 4 + 0];
  const uint4 w1 = p4[t * 4 + 1];
  const uint4 w2 = p4[t * 4 + 2];
  const uint4 w3 = p4[t * 4 + 3];
  const float4 dv0 = compute_delta(r0, gtb[mi0]);
  const float4 dv1 = compute_delta(r1, gtb[mi1]);

  for (int j = t; j < 1280; j += 256) hist[j] = 0u;
  if (t == 0) { s_thr = 0; s_take = 0; scan[256] = 0u; }
  __syncthreads();                                      // B1

  uint32_t rv[16];                       // thread t owns row rois t*16..+15
  rv[0] = w0.x >> 7;  rv[1] = w0.y >> 7;  rv[2] = w0.z >> 7;  rv[3] = w0.w >> 7;
  rv[4] = w1.x >> 7;  rv[5] = w1.y >> 7;  rv[6] = w1.z >> 7;  rv[7] = w1.w >> 7;
  rv[8] = w2.x >> 7;  rv[9] = w2.y >> 7;  rv[10] = w2.z >> 7; rv[11] = w2.w >> 7;
  rv[12] = w3.x >> 7; rv[13] = w3.y >> 7; rv[14] = w3.z >> 7; rv[15] = w3.w >> 7;
  #pragma unroll
  for (int k = 0; k < 16; ++k)
    if (rv[k]) atomicAdd(&hist[rv[k]], 1u);
  __syncthreads();                                      // B2

  // suffix sums over 5-bin chunks (wave shfl + cross-wave LDS)
  uint32_t chunk = 0;
  #pragma unroll
  for (int j = 0; j < 5; ++j) chunk += hist[t * 5 + j];
  uint32_t v = chunk;
  #pragma unroll
  for (int off = 1; off < 64; off <<= 1) {
    const uint32_t u = __shfl_down(v, off);
    if (lane + off < 64) v += u;
  }
  if (lane == 0) wsum[wid] = v;
  __syncthreads();                                      // B3
  {
    uint32_t add = 0;
    #pragma unroll
    for (int w = 0; w < 4; ++w)
      if (w > wid) add += wsum[w];
    v += add;
  }
  scan[t] = v;
  __syncthreads();                                      // B4
  const uint32_t total = scan[0];
  if (total > 128u) {
    const uint32_t Sc = v;
    const uint32_t Sn = scan[t + 1];
    if (Sc >= 128u && Sn < 128u) {
      uint32_t s = Sn;
      #pragma unroll
      for (int j = 4; j >= 0; --j) {
        const uint32_t h = hist[t * 5 + j];
        if (s + h >= 128u) { s_thr = t * 5 + j; s_take = 128 - (int)s; break; }
        s += h;
      }
    }
  }
  __syncthreads();                                      // B5
  const uint32_t thr = (uint32_t)s_thr;
  const uint32_t take = (uint32_t)s_take;

  // exclusive prefix of tie counts (wave shfl + cross-wave LDS)
  uint32_t lt = 0;
  if (thr > 0) {
    #pragma unroll
    for (int k = 0; k < 16; ++k) lt += (rv[k] == thr) ? 1u : 0u;
  }
  uint32_t p = lt;
  #pragma unroll
  for (int off = 1; off < 64; off <<= 1) {
    const uint32_t u = __shfl_up(p, off);
    if (lane >= off) p += u;
  }
  if (lane == 63) wsum[wid] = p;
  __syncthreads();                                      // B6
  uint32_t run = p - lt;
  #pragma unroll
  for (int w = 0; w < 4; ++w)
    if (w < wid) run += wsum[w];

  // decisions: only owner threads of this block's 512 rois store selb
  const int ownerlo = wbase >> 4;        // 32 owner threads
  const bool owner = (t >= ownerlo) && (t < ownerlo + 32);
  #pragma unroll
  for (int k = 0; k < 16; ++k) {
    bool s;
    if (thr == 0) {                      // total <= 128: keep all masked
      s = rv[k] > 0u;
    } else {
      s = (rv[k] > thr);
      if (rv[k] == thr) { s = (run < take); ++run; }
    }
    if (owner) selb[(t - ownerlo) * 16 + k] = s ? 1 : 0;
  }
  __syncthreads();                                      // B7

  const float4 z = {0.f, 0.f, 0.f, 0.f};
  // ---- window 0 ----
  sdv[t] = dv0;
  slbl[t] = selb[t] ? lbl0g : -1;
  __syncthreads();                                      // B8
  {
    const size_t ri0 = (size_t)b * NN + wbase;
    float4* dbase = (float4*)out + ri0 * LL;
    #pragma unroll
    for (int k = 0; k < LL; ++k) {
      const int q = t + k * 256;
      const int rr = q / 21;
      const int f = q - rr * 21;
      dbase[q] = (f == slbl[rr]) ? sdv[rr] : z;
    }
    float4* lbase = (float4*)(out + DELTA_ELEMS) + ri0 * LL / 4;
    for (int q = t; q < 1344; q += 256) {
      const int e0 = q * 4;
      float4 vv;
      const int r0i = e0 / 21;       vv.x = ((e0 - r0i * 21) == slbl[r0i]) ? 1.f : 0.f;
      const int r1i = (e0 + 1) / 21; vv.y = ((e0 + 1 - r1i * 21) == slbl[r1i]) ? 1.f : 0.f;
      const int r2i = (e0 + 2) / 21; vv.z = ((e0 + 2 - r2i * 21) == slbl[r2i]) ? 1.f : 0.f;
      const int r3i = (e0 + 3) / 21; vv.w = ((e0 + 3 - r3i * 21) == slbl[r3i]) ? 1.f : 0.f;
      lbase[q] = vv;
    }
  }
  __syncthreads();                                      // B9
  // ---- window 1 ----
  sdv[t] = dv1;
  slbl[t] = selb[256 + t] ? lbl1g : -1;
  __syncthreads();                                      // B10
  {
    const size_t ri0 = (size_t)b * NN + wbase + 256;
    float4* dbase = (float4*)out + ri0 * LL;
    #pragma unroll
    for (int k = 0; k < LL; ++k) {
      const int q = t + k * 256;
      const int rr = q / 21;
      const int f = q - rr * 21;
      dbase[q] = (f == slbl[rr]) ? sdv[rr] : z;
    }
    float4* lbase = (float4*)(out + DELTA_ELEMS) + ri0 * LL / 4;
    for (int q = t; q < 1344; q += 256) {
      const int e0 = q * 4;
      float4 vv;
      const int r0i = e0 / 21;       vv.x = ((e0 - r0i * 21) == slbl[r0i]) ? 1.f : 0.f;
      const int r1i = (e0 + 1) / 21; vv.y = ((e0 + 1 - r1i * 21) == slbl[r1i]) ? 1.f : 0.f;
      const int r2i = (e0 + 2) / 21; vv.z = ((e0 + 2 - r2i * 21) == slbl[r2i]) ? 1.f : 0.f;
      const int r3i = (e0 + 3) / 21; vv.w = ((e0 + 3 - r3i * 21) == slbl[r3i]) ? 1.f : 0.f;
      lbase[q] = vv;
    }
  }
}

// ================= Slots-mode fallback (r4 proven, ws too small) =================
__global__ __launch_bounds__(256) void iou_kernel_s(const float* __restrict__ roi,
                                                    const float* __restrict__ gt,
                                                    int* __restrict__ midx,
                                                    float* __restrict__ merged) {
  __shared__ float4 gtb[MM];
  const int b = blockIdx.y;
  const int t = threadIdx.x;
  if (t < MM) gtb[t] = ((const float4*)gt)[b * MM + t];
  __syncthreads();
  const int i = b * NN + blockIdx.x * 256 + t;
  const float4 r = ((const float4*)roi)[i];
  const float barea = (r.z - r.x) * (r.w - r.y);
  float best = -1.0f;
  int bm = 0;
  for (int m = 0; m < MM; ++m) {
    const float4 g = gtb[m];
    const float garea = (g.z - g.x) * (g.w - g.y);
    const float xt = fmaxf(r.y, g.y);
    const float yt = fmaxf(r.x, g.x);
    const float xb = fminf(r.w, g.w);
    const float yb = fminf(r.z, g.z);
    const float inter = fmaxf(xb - xt, 0.0f) * fmaxf(yb - yt, 0.0f);
    const float iou = inter / ((barea + garea) - inter);
    if (iou > best) { best = iou; bm = m; }
  }
  midx[(size_t)i * 84] = bm;
  merged[(size_t)i * 84] = best;
}

__global__ __launch_bounds__(256) void select_kernel_s(const float* __restrict__ merged,
                                                       int* __restrict__ sel,
                                                       uint32_t k1a, uint32_t k1b,
                                                       uint32_t k2a, uint32_t k2b) {
  __shared__ uint32_t buf[NN];
  __shared__ uint32_t hist[1280];
  __shared__ uint32_t scan[256];
  __shared__ int s_thr;
  __shared__ int s_take;
  const int b = blockIdx.x;
  const int t = threadIdx.x;
  for (int j = t; j < 1280; j += 256) hist[j] = 0u;
  if (t == 0) { s_thr = 0; s_take = 0; }
  #pragma unroll
  for (int k = 0; k < 16; ++k) {
    const int li = t + k * 256;
    buf[li] = __float_as_uint(merged[(size_t)(b * NN + li) * 84]);
  }
  __syncthreads();
  uint32_t rv[16];
  const int lbase = t * 16;
  #pragma unroll
  for (int k = 0; k < 16; ++k) {
    const int li = lbase + k;
    uint32_t r = 0u;
    if (__uint_as_float(buf[li]) > 0.5f) {
      r = jax_randint_1_1280(k1a, k1b, k2a, k2b, (uint32_t)(b * NN + li));
      atomicAdd(&hist[r], 1u);
    }
    rv[k] = r;
  }
  __syncthreads();
  uint32_t chunk = 0;
  #pragma unroll
  for (int j = 0; j < 5; ++j) chunk += hist[t * 5 + j];
  scan[t] = chunk;
  __syncthreads();
  for (int off = 1; off < 256; off <<= 1) {
    const uint32_t v = (t + off < 256) ? scan[t + off] : 0u;
    __syncthreads();
    scan[t] += v;
    __syncthreads();
  }
  const uint32_t total = scan[0];
  if (total > 128u) {
    const uint32_t Sc = scan[t];
    const uint32_t Sn = (t < 255) ? scan[t + 1] : 0u;
    if (Sc >= 128u && Sn < 128u) {
      uint32_t s = Sn;
      #pragma unroll
      for (int j = 4; j >= 0; --j) {
        const uint32_t h = hist[t * 5 + j];
        if (s + h >= 128u) { s_thr = t * 5 + j; s_take = 128 - (int)s; break; }
        s += h;
      }
    }
  }
  __syncthreads();
  const int thr = s_thr;
  const uint32_t take = (uint32_t)s_take;
  uint32_t lt = 0;
  if (thr > 0) {
    #pragma unroll
    for (int k = 0; k < 16; ++k) lt += (rv[k] == (uint32_t)thr) ? 1u : 0u;
  }
  scan[t] = lt;
  __syncthreads();
  for (int off = 1; off < 256; off <<= 1) {
    const uint32_t v = (t >= off) ? scan[t - off] : 0u;
    __syncthreads();
    scan[t] += v;
    __syncthreads();
  }
  uint32_t run = scan[t] - lt;
  #pragma unroll
  for (int k = 0; k < 16; ++k) {
    bool s;
    if (thr == 0) {
      s = rv[k] > 0u;
    } else {
      s = (rv[k] > (uint32_t)thr);
      if (rv[k] == (uint32_t)thr) { s = (run < take); ++run; }
    }
    buf[lbase + k] = s ? 1u : 0u;
  }
  __syncthreads();
  #pragma unroll
  for (int k = 0; k < 16; ++k) {
    const int li = t + k * 256;
    sel[(size_t)(b * NN + li) * 84] = (int)buf[li];
  }
}

__global__ __launch_bounds__(256) void out_kernel_s(const float* __restrict__ roi,
                                                    const float* __restrict__ gt,
                                                    const int* __restrict__ glab,
                                                    const int* __restrict__ midx,
                                                    const int* __restrict__ sel,
                                                    float* __restrict__ out) {
  __shared__ float4 sdv[256];
  __shared__ int slbl[256];
  const int t = threadIdx.x;
  const int ri0 = blockIdx.x * 256;
  const int i = ri0 + t;
  const int b = i >> 12;
  const int mi = midx[(size_t)i * 84];
  const int sv = sel[(size_t)i * 84];
  float4 dv = {0.f, 0.f, 0.f, 0.f};
  int lbl = -1;
  if (sv) {
    const float4 r = ((const float4*)roi)[i];
    const float4 g = ((const float4*)gt)[b * MM + mi];
    lbl = glab[b * MM + mi];
    dv = compute_delta(r, g);
  }
  sdv[t] = dv;
  slbl[t] = lbl;
  __syncthreads();
  const float4 z = {0.f, 0.f, 0.f, 0.f};
  float4* dbase = (float4*)out + (size_t)ri0 * LL;
  #pragma unroll
  for (int k = 0; k < LL; ++k) {
    const int q = t + k * 256;
    const int r = q / 21;
    const int f = q - r * 21;
    dbase[q] = (f == slbl[r]) ? sdv[r] : z;
  }
  float4* lbase = (float4*)(out + DELTA_ELEMS) + (size_t)ri0 * LL / 4;
  for (int q = t; q < 1344; q += 256) {
    const int e0 = q * 4;
    float4 v;
    const int r0 = e0 / 21;       v.x = ((e0 - r0 * 21) == slbl[r0]) ? 1.f : 0.f;
    const int r1 = (e0 + 1) / 21; v.y = ((e0 + 1 - r1 * 21) == slbl[r1]) ? 1.f : 0.f;
    const int r2 = (e0 + 2) / 21; v.z = ((e0 + 2 - r2 * 21) == slbl[r2]) ? 1.f : 0.f;
    const int r3 = (e0 + 3) / 21; v.w = ((e0 + 3 - r3 * 21) == slbl[r3]) ? 1.f : 0.f;
    lbase[q] = v;
  }
}

extern "C" void kernel_launch(void* const* d_in, const int* in_sizes, int n_in,
                              void* d_out, int out_size, void* d_ws, size_t ws_size,
                              hipStream_t stream) {
  const float* roi = (const float*)d_in[0];
  const float* gt  = (const float*)d_in[1];
  const int* glab  = (const int*)d_in[2];
  float* out = (float*)d_out;

  // Host-side JAX key derivation (foldlike split):
  // key(42)=(0,42); kp=threefry(key,(0,0)); hi=threefry(kp,(0,0)); lo=threefry(kp,(0,1))
  uint32_t kp0, kp1, k1a, k1b, k2a, k2b;
  threefry2x32(0u, 42u, 0u, 0u, &kp0, &kp1);
  threefry2x32(kp0, kp1, 0u, 0u, &k1a, &k1b);
  threefry2x32(kp0, kp1, 0u, 1u, &k2a, &k2b);

  if (d_ws != nullptr && ws_size >= (size_t)NTOT * 4 + 256) {
    uint32_t* packed = (uint32_t*)d_ws;
    uint32_t* barA = (uint32_t*)((char*)d_ws + (size_t)NTOT * 4);
    uint32_t* barB = barA + 32;                     // 128 B apart, never written
    hipLaunchKernelGGL(mega_kernel, dim3(NBLK), dim3(256), 0, stream,
                       roi, gt, glab, packed, barA, barB, out,
                       k1a, k1b, k2a, k2b);
  } else {
    int* midx     = (int*)out;          // slot0 of each 84-float block
    float* merged = out + 1;            // slot1
    int* sel      = (int*)out + 2;      // slot2
    hipLaunchKernelGGL(iou_kernel_s, dim3(NN / 256, BB), dim3(256), 0, stream,
                       roi, gt, midx, merged);
    hipLaunchKernelGGL(select_kernel_s, dim3(BB), dim3(256), 0, stream,
                       merged, sel, k1a, k1b, k2a, k2b);
    hipLaunchKernelGGL(out_kernel_s, dim3(NTOT / 256), dim3(256), 0, stream,
                       roi, gt, glab, midx, sel, out);
  }
}

// Round 12
// 60.498 us; speedup vs baseline: 1.8586x; 1.8586x over previous
//
#include <hip/hip_runtime.h>
#include <stdint.h>

#pragma clang fp contract(off)

// PRNG: jax_threefry_partitionable 32-bit random_bits = o0 ^ o1 (VERIFIED round 3)
// r8=57.5 (2 kernels). r11 mega single-dispatch: 112us BUT gave counters:
// write phase at 1.0 TB/s, occupancy 21% -> the write leg is WAVE-STARVED, not
// BW-saturated. r12: r8 structure + K2 occupancy fix: launch_bounds(256,8)
// (<=64 VGPR), rv packed 2x16b (8 regs), selb 4096->256B, LDS 11.5KB ->
// 8 blocks/CU = 32 waves/CU during the 110MB write.

#define BB 64
#define NN 4096
#define MM 128
#define LL 21
#define NTOT (BB * NN)                           // 262144 rois
#define DELTA_ELEMS ((size_t)BB * NN * LL * 4)   // 22020096 floats

__host__ __device__ __forceinline__ uint32_t rotl32(uint32_t v, int s) {
  return (v << s) | (v >> (32 - s));
}

// Threefry-2x32, 20 rounds (JAX's threefry2x32).
__host__ __device__ inline void threefry2x32(uint32_t k0, uint32_t k1,
                                             uint32_t x0, uint32_t x1,
                                             uint32_t* o0, uint32_t* o1) {
  const uint32_t ks2 = k0 ^ k1 ^ 0x1BD11BDAu;
  x0 += k0; x1 += k1;
#define TF_R(r) do { x0 += x1; x1 = rotl32(x1, (r)); x1 ^= x0; } while (0)
  TF_R(13); TF_R(15); TF_R(26); TF_R(6);
  x0 += k1;  x1 += ks2 + 1u;
  TF_R(17); TF_R(29); TF_R(16); TF_R(24);
  x0 += ks2; x1 += k0 + 2u;
  TF_R(13); TF_R(15); TF_R(26); TF_R(6);
  x0 += k0;  x1 += k1 + 3u;
  TF_R(17); TF_R(29); TF_R(16); TF_R(24);
  x0 += k1;  x1 += ks2 + 4u;
  TF_R(13); TF_R(15); TF_R(26); TF_R(6);
  x0 += ks2; x1 += k0 + 5u;
#undef TF_R
  *o0 = x0; *o1 = x1;
}

__device__ __forceinline__ uint32_t jax_bits32(uint32_t ka, uint32_t kb, uint32_t idx) {
  uint32_t o0, o1;
  threefry2x32(ka, kb, 0u, idx, &o0, &o1);   // counter (hi=0, lo=idx)
  return o0 ^ o1;                            // partitionable 32-bit fold
}

// jax.random.randint(key, (B,N), 1, 1280): span=1279, mult=(2^16%1279)^2%1279=882
__device__ __forceinline__ uint32_t jax_randint_1_1280(uint32_t k1a, uint32_t k1b,
                                                       uint32_t k2a, uint32_t k2b,
                                                       uint32_t idx) {
  const uint32_t hi = jax_bits32(k1a, k1b, idx);
  const uint32_t lo = jax_bits32(k2a, k2b, idx);
  const uint32_t off = ((hi % 1279u) * 882u + (lo % 1279u)) % 1279u;
  return 1u + off;
}

__device__ __forceinline__ float4 compute_delta(const float4 r, const float4 g) {
  float bh = r.z - r.x, bw = r.w - r.y;
  const float bcy = r.x + 0.5f * bh, bcx = r.y + 0.5f * bw;
  const float gh = g.z - g.x, gw = g.w - g.y;
  const float gcy = g.x + 0.5f * gh, gcx = g.y + 0.5f * gw;
  if (bw == 0.0f) bw = 1e-3f;
  if (bh == 0.0f) bh = 1e-3f;
  const float dx = (gcx - bcx) / bw;
  const float dy = (gcy - bcy) / bh;
  const float dw = (gw == 0.0f) ? 0.0f : logf(gw / bw);
  const float dh = (gh == 0.0f) ? 0.0f : logf(gh / bh);
  float4 dv;
  dv.x = dy / 0.1f; dv.y = dx / 0.1f; dv.z = dh / 0.2f; dv.w = dw / 0.2f;
  return dv;
}

// ---------- K1: IoU argmax + randint, packed to 4B/roi (r8 verbatim) ----------
// pk = midx(7b) | rand<<7 (rand=0 iff merged<=0.5; rand in [1,1279] fits 11b)
__global__ __launch_bounds__(256) void iou_pack_kernel(
    const float* __restrict__ roi, const float* __restrict__ gt,
    uint32_t* __restrict__ packed,
    uint32_t k1a, uint32_t k1b, uint32_t k2a, uint32_t k2b) {
  __shared__ float4 gtb[MM];
  __shared__ float gar[MM];
  const int b = blockIdx.y;
  const int t = threadIdx.x;
  if (t < MM) {
    const float4 g = ((const float4*)gt)[b * MM + t];
    gtb[t] = g;
    gar[t] = (g.z - g.x) * (g.w - g.y);
  }
  __syncthreads();
  const int i = b * NN + blockIdx.x * 256 + t;
  const float4 r = ((const float4*)roi)[i];           // [y1,x1,y2,x2]
  const float barea = (r.z - r.x) * (r.w - r.y);
  float best = -1.0f;
  int bm = 0;
  for (int m = 0; m < MM; ++m) {
    const float4 g = gtb[m];
    const float xt = fmaxf(r.y, g.y);
    const float yt = fmaxf(r.x, g.x);
    const float xb = fminf(r.w, g.w);
    const float yb = fminf(r.z, g.z);
    const float inter = fmaxf(xb - xt, 0.0f) * fmaxf(yb - yt, 0.0f);
    const float uni = (barea + gar[m]) - inter;
    const float iou = inter / uni;                    // IEEE div, bit-exact vs ref
    if (iou > best) { best = iou; bm = m; }           // first-occurrence argmax
  }
  const uint32_t rnd = jax_randint_1_1280(k1a, k1b, k2a, k2b, (uint32_t)i);
  packed[i] = (uint32_t)bm | ((best > 0.5f) ? (rnd << 7) : 0u);
}

// ---------- K2: select-recompute + coalesced write, occupancy-tuned ----------
// 16 blocks per row; each re-derives the row's thr/take/tie-ranks from packed,
// then writes its 256-roi region. <=64 VGPR (launch_bounds 8 waves/EU),
// 11.5KB LDS -> 8 blocks/CU = 32 waves/CU for the streaming write.
__global__ __launch_bounds__(256, 8) void fused_out_kernel(
    const float* __restrict__ roi, const float* __restrict__ gt,
    const int* __restrict__ glab, const uint32_t* __restrict__ packed,
    float* __restrict__ out) {
  __shared__ uint32_t hist[1280];
  __shared__ uint32_t scan[256];
  __shared__ unsigned char selb[256];   // this block's window only
  __shared__ float4 sdv[256];
  __shared__ int slbl[256];
  __shared__ int s_thr;
  __shared__ int s_take;
  const int br = blockIdx.x;
  const int b = br >> 4;                // row
  const int win0 = (br & 15) << 8;      // this block's 256-roi window
  const int t = threadIdx.x;
  for (int j = t; j < 1280; j += 256) hist[j] = 0u;
  if (t == 0) { s_thr = 0; s_take = 0; }
  __syncthreads();

  // Phase B: thread t owns row rois t*16..t*16+15 (tie order!).
  // rands are 11-bit -> pack 2 per register (rvp[8]) to cut VGPR pressure.
  uint32_t rvp[8];
  const uint4* p4 = (const uint4*)(packed + (size_t)b * NN);
  #pragma unroll
  for (int q = 0; q < 4; ++q) {
    const uint4 w = p4[t * 4 + q];
    const uint32_t a0 = w.x >> 7, a1 = w.y >> 7, a2 = w.z >> 7, a3 = w.w >> 7;
    rvp[q * 2]     = a0 | (a1 << 16);
    rvp[q * 2 + 1] = a2 | (a3 << 16);
    if (a0) atomicAdd(&hist[a0], 1u);
    if (a1) atomicAdd(&hist[a1], 1u);
    if (a2) atomicAdd(&hist[a2], 1u);
    if (a3) atomicAdd(&hist[a3], 1u);
  }
  __syncthreads();

  // Phase C: suffix sums over 5-bin chunks: scan[t] = sum_{j>=t*5} hist[j]
  uint32_t chunk = 0;
  #pragma unroll
  for (int j = 0; j < 5; ++j) chunk += hist[t * 5 + j];
  scan[t] = chunk;
  __syncthreads();
  for (int off = 1; off < 256; off <<= 1) {
    const uint32_t v = (t + off < 256) ? scan[t + off] : 0u;
    __syncthreads();
    scan[t] += v;
    __syncthreads();
  }
  const uint32_t total = scan[0];
  if (total > 128u) {
    const uint32_t Sc = scan[t];
    const uint32_t Sn = (t < 255) ? scan[t + 1] : 0u;
    if (Sc >= 128u && Sn < 128u) {       // threshold bin lives in my chunk
      uint32_t s = Sn;
      #pragma unroll
      for (int j = 4; j >= 0; --j) {
        const uint32_t h = hist[t * 5 + j];
        if (s + h >= 128u) { s_thr = t * 5 + j; s_take = 128 - (int)s; break; }
        s += h;
      }
    }
  }
  __syncthreads();
  const uint32_t thr = (uint32_t)s_thr;
  const uint32_t take = (uint32_t)s_take;

  // Phase D: exclusive prefix of tie counts (ascending index), then sel bits
  uint32_t lt = 0;
  if (thr > 0) {
    #pragma unroll
    for (int q = 0; q < 8; ++q) {
      lt += ((rvp[q] & 0xFFFFu) == thr) ? 1u : 0u;
      lt += ((rvp[q] >> 16) == thr) ? 1u : 0u;
    }
  }
  scan[t] = lt;
  __syncthreads();
  for (int off = 1; off < 256; off <<= 1) {
    const uint32_t v = (t >= off) ? scan[t - off] : 0u;
    __syncthreads();
    scan[t] += v;
    __syncthreads();
  }
  uint32_t run = scan[t] - lt;           // exclusive prefix of ties before me

  #pragma unroll
  for (int k = 0; k < 16; ++k) {
    const uint32_t val = (k & 1) ? (rvp[k >> 1] >> 16) : (rvp[k >> 1] & 0xFFFFu);
    bool s;
    if (thr == 0) {                      // total <= 128: keep all masked
      s = val > 0u;
    } else {
      s = (val > thr);
      if (val == thr) { s = (run < take); ++run; }
    }
    const int wloc = t * 16 + k - win0;  // position within this block's window
    if ((unsigned)wloc < 256u) selb[wloc] = s ? 1 : 0;
  }
  __syncthreads();

  // Phase E: this window's per-roi delta/label, then coalesced region write
  const int irow = win0 + t;
  const int i = b * NN + irow;
  float4 dv = {0.f, 0.f, 0.f, 0.f};
  int lbl = -1;
  if (selb[t]) {
    const int mi = (int)(packed[i] & 127u);
    const float4 r = ((const float4*)roi)[i];
    const float4 g = ((const float4*)gt)[b * MM + mi];
    lbl = glab[b * MM + mi];
    dv = compute_delta(r, g);
  }
  sdv[t] = dv;
  slbl[t] = lbl;
  __syncthreads();
  const float4 z = {0.f, 0.f, 0.f, 0.f};
  const size_t ri0 = (size_t)b * NN + win0;
  float4* dbase = (float4*)out + ri0 * LL;      // 5376 float4 region
  #pragma unroll
  for (int k = 0; k < LL; ++k) {
    const int q = t + k * 256;
    const int rr = q / 21;
    const int f = q - rr * 21;
    dbase[q] = (f == slbl[rr]) ? sdv[rr] : z;
  }
  float4* lbase = (float4*)(out + DELTA_ELEMS) + ri0 * LL / 4;  // 1344 float4
  for (int q = t; q < 1344; q += 256) {
    const int e0 = q * 4;
    float4 vv;
    const int r0 = e0 / 21;       vv.x = ((e0 - r0 * 21) == slbl[r0]) ? 1.f : 0.f;
    const int r1 = (e0 + 1) / 21; vv.y = ((e0 + 1 - r1 * 21) == slbl[r1]) ? 1.f : 0.f;
    const int r2 = (e0 + 2) / 21; vv.z = ((e0 + 2 - r2 * 21) == slbl[r2]) ? 1.f : 0.f;
    const int r3 = (e0 + 3) / 21; vv.w = ((e0 + 3 - r3 * 21) == slbl[r3]) ? 1.f : 0.f;
    lbase[q] = vv;
  }
}

// ================= Slots-mode fallback (r4 proven, ws too small) =================
__global__ __launch_bounds__(256) void iou_kernel_s(const float* __restrict__ roi,
                                                    const float* __restrict__ gt,
                                                    int* __restrict__ midx,
                                                    float* __restrict__ merged) {
  __shared__ float4 gtb[MM];
  const int b = blockIdx.y;
  const int t = threadIdx.x;
  if (t < MM) gtb[t] = ((const float4*)gt)[b * MM + t];
  __syncthreads();
  const int i = b * NN + blockIdx.x * 256 + t;
  const float4 r = ((const float4*)roi)[i];
  const float barea = (r.z - r.x) * (r.w - r.y);
  float best = -1.0f;
  int bm = 0;
  for (int m = 0; m < MM; ++m) {
    const float4 g = gtb[m];
    const float garea = (g.z - g.x) * (g.w - g.y);
    const float xt = fmaxf(r.y, g.y);
    const float yt = fmaxf(r.x, g.x);
    const float xb = fminf(r.w, g.w);
    const float yb = fminf(r.z, g.z);
    const float inter = fmaxf(xb - xt, 0.0f) * fmaxf(yb - yt, 0.0f);
    const float iou = inter / ((barea + garea) - inter);
    if (iou > best) { best = iou; bm = m; }
  }
  midx[(size_t)i * 84] = bm;
  merged[(size_t)i * 84] = best;
}

__global__ __launch_bounds__(256) void select_kernel_s(const float* __restrict__ merged,
                                                       int* __restrict__ sel,
                                                       uint32_t k1a, uint32_t k1b,
                                                       uint32_t k2a, uint32_t k2b) {
  __shared__ uint32_t buf[NN];
  __shared__ uint32_t hist[1280];
  __shared__ uint32_t scan[256];
  __shared__ int s_thr;
  __shared__ int s_take;
  const int b = blockIdx.x;
  const int t = threadIdx.x;
  for (int j = t; j < 1280; j += 256) hist[j] = 0u;
  if (t == 0) { s_thr = 0; s_take = 0; }
  #pragma unroll
  for (int k = 0; k < 16; ++k) {
    const int li = t + k * 256;
    buf[li] = __float_as_uint(merged[(size_t)(b * NN + li) * 84]);
  }
  __syncthreads();
  uint32_t rv[16];
  const int lbase = t * 16;
  #pragma unroll
  for (int k = 0; k < 16; ++k) {
    const int li = lbase + k;
    uint32_t r = 0u;
    if (__uint_as_float(buf[li]) > 0.5f) {
      r = jax_randint_1_1280(k1a, k1b, k2a, k2b, (uint32_t)(b * NN + li));
      atomicAdd(&hist[r], 1u);
    }
    rv[k] = r;
  }
  __syncthreads();
  uint32_t chunk = 0;
  #pragma unroll
  for (int j = 0; j < 5; ++j) chunk += hist[t * 5 + j];
  scan[t] = chunk;
  __syncthreads();
  for (int off = 1; off < 256; off <<= 1) {
    const uint32_t v = (t + off < 256) ? scan[t + off] : 0u;
    __syncthreads();
    scan[t] += v;
    __syncthreads();
  }
  const uint32_t total = scan[0];
  if (total > 128u) {
    const uint32_t Sc = scan[t];
    const uint32_t Sn = (t < 255) ? scan[t + 1] : 0u;
    if (Sc >= 128u && Sn < 128u) {
      uint32_t s = Sn;
      #pragma unroll
      for (int j = 4; j >= 0; --j) {
        const uint32_t h = hist[t * 5 + j];
        if (s + h >= 128u) { s_thr = t * 5 + j; s_take = 128 - (int)s; break; }
        s += h;
      }
    }
  }
  __syncthreads();
  const int thr = s_thr;
  const uint32_t take = (uint32_t)s_take;
  uint32_t lt = 0;
  if (thr > 0) {
    #pragma unroll
    for (int k = 0; k < 16; ++k) lt += (rv[k] == (uint32_t)thr) ? 1u : 0u;
  }
  scan[t] = lt;
  __syncthreads();
  for (int off = 1; off < 256; off <<= 1) {
    const uint32_t v = (t >= off) ? scan[t - off] : 0u;
    __syncthreads();
    scan[t] += v;
    __syncthreads();
  }
  uint32_t run = scan[t] - lt;
  #pragma unroll
  for (int k = 0; k < 16; ++k) {
    bool s;
    if (thr == 0) {
      s = rv[k] > 0u;
    } else {
      s = (rv[k] > (uint32_t)thr);
      if (rv[k] == (uint32_t)thr) { s = (run < take); ++run; }
    }
    buf[lbase + k] = s ? 1u : 0u;
  }
  __syncthreads();
  #pragma unroll
  for (int k = 0; k < 16; ++k) {
    const int li = t + k * 256;
    sel[(size_t)(b * NN + li) * 84] = (int)buf[li];
  }
}

__global__ __launch_bounds__(256) void out_kernel_s(const float* __restrict__ roi,
                                                    const float* __restrict__ gt,
                                                    const int* __restrict__ glab,
                                                    const int* __restrict__ midx,
                                                    const int* __restrict__ sel,
                                                    float* __restrict__ out) {
  __shared__ float4 sdv[256];
  __shared__ int slbl[256];
  const int t = threadIdx.x;
  const int ri0 = blockIdx.x * 256;
  const int i = ri0 + t;
  const int b = i >> 12;
  const int mi = midx[(size_t)i * 84];
  const int sv = sel[(size_t)i * 84];
  float4 dv = {0.f, 0.f, 0.f, 0.f};
  int lbl = -1;
  if (sv) {
    const float4 r = ((const float4*)roi)[i];
    const float4 g = ((const float4*)gt)[b * MM + mi];
    lbl = glab[b * MM + mi];
    dv = compute_delta(r, g);
  }
  sdv[t] = dv;
  slbl[t] = lbl;
  __syncthreads();
  const float4 z = {0.f, 0.f, 0.f, 0.f};
  float4* dbase = (float4*)out + (size_t)ri0 * LL;
  #pragma unroll
  for (int k = 0; k < LL; ++k) {
    const int q = t + k * 256;
    const int r = q / 21;
    const int f = q - r * 21;
    dbase[q] = (f == slbl[r]) ? sdv[r] : z;
  }
  float4* lbase = (float4*)(out + DELTA_ELEMS) + (size_t)ri0 * LL / 4;
  for (int q = t; q < 1344; q += 256) {
    const int e0 = q * 4;
    float4 v;
    const int r0 = e0 / 21;       v.x = ((e0 - r0 * 21) == slbl[r0]) ? 1.f : 0.f;
    const int r1 = (e0 + 1) / 21; v.y = ((e0 + 1 - r1 * 21) == slbl[r1]) ? 1.f : 0.f;
    const int r2 = (e0 + 2) / 21; v.z = ((e0 + 2 - r2 * 21) == slbl[r2]) ? 1.f : 0.f;
    const int r3 = (e0 + 3) / 21; v.w = ((e0 + 3 - r3 * 21) == slbl[r3]) ? 1.f : 0.f;
    lbase[q] = v;
  }
}

extern "C" void kernel_launch(void* const* d_in, const int* in_sizes, int n_in,
                              void* d_out, int out_size, void* d_ws, size_t ws_size,
                              hipStream_t stream) {
  const float* roi = (const float*)d_in[0];
  const float* gt  = (const float*)d_in[1];
  const int* glab  = (const int*)d_in[2];
  float* out = (float*)d_out;

  // Host-side JAX key derivation (foldlike split):
  // key(42)=(0,42); kp=threefry(key,(0,0)); hi=threefry(kp,(0,0)); lo=threefry(kp,(0,1))
  uint32_t kp0, kp1, k1a, k1b, k2a, k2b;
  threefry2x32(0u, 42u, 0u, 0u, &kp0, &kp1);
  threefry2x32(kp0, kp1, 0u, 0u, &k1a, &k1b);
  threefry2x32(kp0, kp1, 0u, 1u, &k2a, &k2b);

  if (d_ws != nullptr && ws_size >= (size_t)NTOT * 4) {
    uint32_t* packed = (uint32_t*)d_ws;
    hipLaunchKernelGGL(iou_pack_kernel, dim3(NN / 256, BB), dim3(256), 0, stream,
                       roi, gt, packed, k1a, k1b, k2a, k2b);
    hipLaunchKernelGGL(fused_out_kernel, dim3(NTOT / 256), dim3(256), 0, stream,
                       roi, gt, glab, packed, out);
  } else {
    int* midx     = (int*)out;          // slot0 of each 84-float block
    float* merged = out + 1;            // slot1
    int* sel      = (int*)out + 2;      // slot2
    hipLaunchKernelGGL(iou_kernel_s, dim3(NN / 256, BB), dim3(256), 0, stream,
                       roi, gt, midx, merged);
    hipLaunchKernelGGL(select_kernel_s, dim3(BB), dim3(256), 0, stream,
                       merged, sel, k1a, k1b, k2a, k2b);
    hipLaunchKernelGGL(out_kernel_s, dim3(NTOT / 256), dim3(256), 0, stream,
                       roi, gt, glab, midx, sel, out);
  }
}